// Round 2
// baseline (213.021 us; speedup 1.0000x reference)
//
#include <hip/hip_runtime.h>
#include <hip/hip_bf16.h>

typedef __bf16 bf16;
typedef __attribute__((ext_vector_type(8))) __bf16 bf16x8;
typedef __attribute__((ext_vector_type(4))) __bf16 bf16x4;
typedef __attribute__((ext_vector_type(2))) __bf16 bf16x2;
typedef __attribute__((ext_vector_type(4))) float f32x4;

#define C_NODES 63
#define F_DIM   250
#define NEG_SLOPE 0.2f

// LDS byte offsets
#define OFF_AFR   0        // 32 KB: packed X A-frags; later Hs[f][s] col-major bf16 (swizzled)
#define OFF_ALPHA 32768    // 8 KB: alpha [64 d][64 s] bf16 (swizzled)
#define OFF_AS    40960    // 64 f32
#define OFF_AD    41216    // 64 f32
#define OFF_PS    41472    // 4x64 f32 partial src scores
#define OFF_PD    42496    // 4x64 f32 partial dst scores
#define OFF_MAX   43520    // 1 f32
#define OFF_ATTS  43524    // 250 f32 (padded 1024 B)
#define OFF_ATTD  44548    // 250 f32
#define LDS_BYTES 45632

// XOR swizzle for [row][128B-row-stride] layouts: moves 16B block by row&7.
// Bijective involution; identical formula on write and read sides.
__device__ __forceinline__ int swz(int a) { return a ^ ((a >> 3) & 0x70); }

// Pack W (250x250 f32) into bf16 MFMA-B fragment order, zero-padded to 256x256.
// Element i = tile*512 + lane*8 + j ; tile = kt*16+nt ;
// holds W[kt*32 + (lane>>4)*8 + j][nt*16 + (lane&15)]
extern "C" __global__ __launch_bounds__(256)
void gat_prep(const float* __restrict__ W, bf16* __restrict__ Wp) {
    int i = blockIdx.x * 256 + threadIdx.x;   // 0..65535
    int tile = i >> 9;
    int ln   = (i >> 3) & 63;
    int j    = i & 7;
    int kt = tile >> 4, nt = tile & 15;
    int k = kt * 32 + (ln >> 4) * 8 + j;
    int n = nt * 16 + (ln & 15);
    float v = (k < F_DIM && n < F_DIM) ? W[k * F_DIM + n] : 0.f;
    Wp[i] = (bf16)v;
}

extern "C" __global__ __launch_bounds__(256, 3)
void gat_main(const float* __restrict__ x, const bf16* __restrict__ Wp,
              const float* __restrict__ att_src, const float* __restrict__ att_dst,
              const float* __restrict__ bias, float* __restrict__ out)
{
    __shared__ __align__(16) unsigned char smem[LDS_BYTES];
    const int tid  = threadIdx.x;
    const int lane = tid & 63;
    const int w    = tid >> 6;        // wave id 0..3 -> owns 64 output columns
    const int b    = blockIdx.x;
    const int fl   = lane & 15;
    const int fh   = lane >> 4;

    // preload this thread's bias columns (overlaps with staging)
    float bv[4];
#pragma unroll
    for (int nti = 0; nti < 4; ++nti) {
        int f = w * 64 + nti * 16 + fl;
        bv[nti] = (f < F_DIM) ? bias[f] : 0.f;
    }

    // zero A-frag region (K/row padding must be 0) + stage att vectors
    {
        f32x4 zero4 = {0.f, 0.f, 0.f, 0.f};
        f32x4* p = (f32x4*)(smem + OFF_AFR);
#pragma unroll
        for (int i = 0; i < 8; ++i) p[tid + i * 256] = zero4;
        float* atts = (float*)(smem + OFF_ATTS);
        float* attd = (float*)(smem + OFF_ATTD);
        if (tid < F_DIM) { atts[tid] = att_src[tid]; attd[tid] = att_dst[tid]; }
    }
    __syncthreads();

    // stage X_b -> bf16, scattered directly into packed A-fragment order:
    // element (r,c) -> tile (mt=r>>4, kt=c>>5), lane=(r&15)|(((c>>3)&3)<<4), j=c&7
    {
        bf16* afr = (bf16*)(smem + OFF_AFR);
        const float2* xb = (const float2*)(x + (size_t)b * (C_NODES * F_DIM));
        for (int i = tid; i < (C_NODES * F_DIM) / 2; i += 256) {
            float2 v = xb[i];
            int e = i * 2;
            int r = e / F_DIM;
            int c = e - r * F_DIM;      // even; pair stays in same 8-elem group
            int mt = r >> 4, kt = c >> 5;
            int dl = (r & 15) | (((c >> 3) & 3) << 4);
            int off = ((mt * 8 + kt) << 9) + dl * 8 + (c & 7);
            bf16x2 pk = { (bf16)v.x, (bf16)v.y };
            *(bf16x2*)(afr + off) = pk;
        }
    }
    __syncthreads();

    // ---- GEMM1: H[64][256] = X @ W  (wave w computes cols w*64..w*64+63) ----
    f32x4 acc[4][4];
#pragma unroll
    for (int mt = 0; mt < 4; ++mt)
#pragma unroll
        for (int nti = 0; nti < 4; ++nti)
            acc[mt][nti] = (f32x4){0.f, 0.f, 0.f, 0.f};
    {
        const bf16x8* afrv = (const bf16x8*)(smem + OFF_AFR);
        const bf16x8* wpv  = (const bf16x8*)Wp;
#pragma unroll 2
        for (int kt = 0; kt < 8; ++kt) {
            bf16x8 af[4], bw[4];
#pragma unroll
            for (int mt = 0; mt < 4; ++mt)
                af[mt] = afrv[(mt * 8 + kt) * 64 + lane];
#pragma unroll
            for (int nti = 0; nti < 4; ++nti)
                bw[nti] = wpv[(kt * 16 + (w * 4 + nti)) * 64 + lane];
#pragma unroll
            for (int mt = 0; mt < 4; ++mt)
#pragma unroll
                for (int nti = 0; nti < 4; ++nti)
                    acc[mt][nti] = __builtin_amdgcn_mfma_f32_16x16x32_bf16(
                        af[mt], bw[nti], acc[mt][nti], 0, 0, 0);
        }
    }
    __syncthreads();   // all waves done reading A-frags before overwrite

    // write H -> LDS column-major Hs[f][s] bf16 (swizzled); C/D frag rows are
    // 4 consecutive s at fixed col -> one 8B store each
    {
#pragma unroll
        for (int mt = 0; mt < 4; ++mt) {
            int s0 = mt * 16 + fh * 4;
#pragma unroll
            for (int nti = 0; nti < 4; ++nti) {
                int f = w * 64 + nti * 16 + fl;
                f32x4 v = acc[mt][nti];
                bf16x4 hv = { (bf16)v.x, (bf16)v.y, (bf16)v.z, (bf16)v.w };
                *(bf16x4*)(smem + swz(OFF_AFR + f * 128 + s0 * 2)) = hv;
            }
        }
    }
    __syncthreads();

    // a_s/a_d partial dots: thread = (source s=lane, f-chunk = w*64..)
    {
        const float* atts = (const float*)(smem + OFF_ATTS);
        const float* attd = (const float*)(smem + OFF_ATTD);
        float psc = 0.f, pdc = 0.f;
        int fbase = w * 64;
        int fmax = (F_DIM - fbase < 64) ? (F_DIM - fbase) : 64;
        for (int ff = 0; ff < fmax; ++ff) {
            int f = fbase + ff;
            float h = (float)*(const bf16*)(smem + swz(OFF_AFR + f * 128 + lane * 2));
            psc = fmaf(h, atts[f], psc);
            pdc = fmaf(h, attd[f], pdc);
        }
        ((float*)(smem + OFF_PS))[w * 64 + lane] = psc;
        ((float*)(smem + OFF_PD))[w * 64 + lane] = pdc;
    }
    __syncthreads();

    // reduce partials; wave 0 also computes max_s a_s (s < 63)
    if (w == 0) {
        const float* ps = (const float*)(smem + OFF_PS);
        const float* pd = (const float*)(smem + OFF_PD);
        float as_ = ps[lane] + ps[64 + lane] + ps[128 + lane] + ps[192 + lane];
        float ad_ = pd[lane] + pd[64 + lane] + pd[128 + lane] + pd[192 + lane];
        ((float*)(smem + OFF_AS))[lane] = as_;
        ((float*)(smem + OFF_AD))[lane] = ad_;
        float m = (lane < C_NODES) ? as_ : -1e30f;
#pragma unroll
        for (int d = 32; d > 0; d >>= 1) m = fmaxf(m, __shfl_xor(m, d));
        if (lane == 0) *(float*)(smem + OFF_MAX) = m;
    }
    __syncthreads();

    // softmax: thread -> (row d = tid>>2, 16-source chunk sq = tid&3)
    // row max via monotonicity: max_s lrelu(a_s+a_d) = lrelu(maxA + a_d)
    {
        const float* as_ = (const float*)(smem + OFF_AS);
        int d  = tid >> 2;
        int sq = tid & 3;
        float ad_v = ((const float*)(smem + OFF_AD))[d];
        float mA   = *(const float*)(smem + OFF_MAX);
        float t0 = mA + ad_v;
        float md = (t0 > 0.f) ? t0 : NEG_SLOPE * t0;
        float p[16]; float sum = 0.f;
#pragma unroll
        for (int k = 0; k < 16; ++k) {
            int s = sq * 16 + k;
            float e = as_[s] + ad_v;
            e = (e > 0.f) ? e : NEG_SLOPE * e;
            float pv = (s < C_NODES) ? __expf(e - md) : 0.f;
            p[k] = pv; sum += pv;
        }
        sum += __shfl_xor(sum, 1);
        sum += __shfl_xor(sum, 2);
        float rz = 1.f / sum;
        bf16x8 pk0, pk1;
#pragma unroll
        for (int k = 0; k < 8; ++k) {
            pk0[k] = (bf16)(p[k] * rz);
            pk1[k] = (bf16)(p[8 + k] * rz);
        }
        int base = OFF_ALPHA + d * 128 + sq * 32;
        *(bf16x8*)(smem + swz(base))      = pk0;
        *(bf16x8*)(smem + swz(base + 16)) = pk1;
    }
    __syncthreads();

    // ---- GEMM2: out[64][256] = alpha[64][64] @ H[64][256] ----
    f32x4 acc2[4][4];
#pragma unroll
    for (int mt = 0; mt < 4; ++mt)
#pragma unroll
        for (int nti = 0; nti < 4; ++nti)
            acc2[mt][nti] = (f32x4){0.f, 0.f, 0.f, 0.f};
    {
#pragma unroll
        for (int ks = 0; ks < 2; ++ks) {
            int kk = ks * 32 + fh * 8;
            bf16x8 aal[4], hbf[4];
#pragma unroll
            for (int mt = 0; mt < 4; ++mt) {
                int dd = mt * 16 + fl;
                aal[mt] = *(const bf16x8*)(smem + swz(OFF_ALPHA + dd * 128 + kk * 2));
            }
#pragma unroll
            for (int nti = 0; nti < 4; ++nti) {
                int f = w * 64 + nti * 16 + fl;
                hbf[nti] = *(const bf16x8*)(smem + swz(OFF_AFR + f * 128 + kk * 2));
            }
#pragma unroll
            for (int mt = 0; mt < 4; ++mt)
#pragma unroll
                for (int nti = 0; nti < 4; ++nti)
                    acc2[mt][nti] = __builtin_amdgcn_mfma_f32_16x16x32_bf16(
                        aal[mt], hbf[nti], acc2[mt][nti], 0, 0, 0);
        }
    }

    // epilogue: + bias, store fp32, mask r<63 / f<250
    float* ob = out + (size_t)b * (C_NODES * F_DIM);
#pragma unroll
    for (int mt = 0; mt < 4; ++mt) {
#pragma unroll
        for (int i = 0; i < 4; ++i) {
            int r = mt * 16 + fh * 4 + i;
            if (r < C_NODES) {
#pragma unroll
                for (int nti = 0; nti < 4; ++nti) {
                    int f = w * 64 + nti * 16 + fl;
                    if (f < F_DIM) ob[r * F_DIM + f] = acc2[mt][nti][i] + bv[nti];
                }
            }
        }
    }
}

extern "C" void kernel_launch(void* const* d_in, const int* in_sizes, int n_in,
                              void* d_out, int out_size, void* d_ws, size_t ws_size,
                              hipStream_t stream) {
    const float* x       = (const float*)d_in[0];
    const float* W       = (const float*)d_in[1];
    const float* att_src = (const float*)d_in[2];
    const float* att_dst = (const float*)d_in[3];
    const float* bias    = (const float*)d_in[4];
    float* out = (float*)d_out;
    bf16* Wp = (bf16*)d_ws;   // 65536 bf16 = 128 KB packed W

    gat_prep<<<256, 256, 0, stream>>>(W, Wp);
    gat_main<<<4096, 256, 0, stream>>>(x, Wp, att_src, att_dst, bias, out);
}

// Round 4
// 147.602 us; speedup vs baseline: 1.4432x; 1.4432x over previous
//
#include <hip/hip_runtime.h>
#include <hip/hip_bf16.h>

typedef __bf16 bf16;
typedef __attribute__((ext_vector_type(8))) __bf16 bf16x8;
typedef __attribute__((ext_vector_type(4))) __bf16 bf16x4;
typedef __attribute__((ext_vector_type(2))) __bf16 bf16x2;
typedef __attribute__((ext_vector_type(4))) float f32x4;

#define C_NODES 63
#define F_DIM   250
#define NEG_SLOPE 0.2f

// LDS layout (40960 B total = exactly 4 blocks/CU at 160 KiB):
//   [0, 32768)     A-fragments of X (GEMM1), then reused as Hs[f][s] bf16,
//                  swizzled row-locally (swz keeps bytes within their 128B row).
//   [32000,32256)  AS: a_s[64] f32  (inside Hs rows 250..255, which are never
//   [32256,32512)  AD: a_d[64] f32   written because Hs writes mask f<250)
//   [32768, 40960) alpha [64 d][64 s] bf16 (swizzled)
#define OFF_AS    32000
#define OFF_AD    32256
#define OFF_ALPHA 32768
#define LDS_BYTES 40960

// XOR swizzle for [row][128B-stride] layouts; bijective involution, and maps
// every byte to another byte of the SAME 128-byte row.
__device__ __forceinline__ int swz(int a) { return a ^ ((a >> 3) & 0x70); }

// Pack W (250x250 f32) into bf16 MFMA-B fragment order, padded to 256x256.
// Columns 250/251 hold ws = W@att_src and wd = W@att_dst, so GEMM1 emits the
// per-node scores a_s, a_d directly. Rows k>=250 are zero (kills A-garbage).
// Element i = tile*512 + lane*8 + j ; tile = kt*16+nt ;
// holds Wp[kt*32 + (lane>>4)*8 + j][nt*16 + (lane&15)]
extern "C" __global__ __launch_bounds__(256)
void gat_prep(const float* __restrict__ W, const float* __restrict__ att_src,
              const float* __restrict__ att_dst, bf16* __restrict__ Wp) {
    int i = blockIdx.x * 256 + threadIdx.x;   // 0..65535
    int tile = i >> 9;
    int ln   = (i >> 3) & 63;
    int j    = i & 7;
    int kt = tile >> 4, nt = tile & 15;
    int k = kt * 32 + (ln >> 4) * 8 + j;
    int n = nt * 16 + (ln & 15);
    float v = 0.f;
    if (k < F_DIM) {
        if (n < F_DIM) {
            v = W[k * F_DIM + n];
        } else if (n == F_DIM || n == F_DIM + 1) {
            const float* att = (n == F_DIM) ? att_src : att_dst;
            float s = 0.f;
            for (int o = 0; o < F_DIM; ++o) s = fmaf(W[k * F_DIM + o], att[o], s);
            v = s;
        }
    }
    Wp[i] = (bf16)v;
}

extern "C" __global__ __launch_bounds__(256, 4)
void gat_main(const float* __restrict__ x, const bf16* __restrict__ Wp,
              const float* __restrict__ bias, float* __restrict__ out)
{
    __shared__ __align__(16) unsigned char smem[LDS_BYTES];
    const int tid  = threadIdx.x;
    const int lane = tid & 63;
    const int w    = tid >> 6;        // wave id 0..3 -> owns 64 output columns
    const int b    = blockIdx.x;
    const int fl   = lane & 15;
    const int fh   = lane >> 4;

    // bias preload (overlaps staging)
    float bv[4];
#pragma unroll
    for (int nti = 0; nti < 4; ++nti) {
        int f = w * 64 + nti * 16 + fl;
        bv[nti] = (f < F_DIM) ? bias[f] : 0.f;
    }

    // NaN-guard: zero the only A-frag slots the scatter never writes.
    // (Everything else garbage-safe: Wp pad rows are 0; row 63 handled here.)
    if (tid < 64) {
        // c in 250..255 tail slots: tile (mt,7), dl=48+fl_, j=2..7 (bytes 4..15)
        int base = (((tid >> 4) * 8 + 7) << 10) + (48 + (tid & 15)) * 16;
        *(unsigned int*)(smem + base + 4) = 0u;
        *(unsigned long long*)(smem + base + 8) = 0ull;
    } else if (tid < 96) {
        // row r=63 slots: tile (3,kt), dl=(fh_<<4)|15, full 16 B
        int idx = tid - 64;
        int base = ((24 + (idx >> 2)) << 10) + ((((idx & 3) << 4) | 15) * 16);
        *(f32x4*)(smem + base) = (f32x4){0.f, 0.f, 0.f, 0.f};
    }

    // stage X_b -> bf16 A-fragments. Exact cover: 63 rows x 32 col-groups,
    // idx = r*32+g, thread does <=8 groups; 16B ds_write_b128 per full group.
    {
        const float* xb = x + (size_t)b * (C_NODES * F_DIM);
#pragma unroll
        for (int it = 0; it < 8; ++it) {
            int idx = tid + it * 256;
            if (idx < 2016) {
                int r = idx >> 5, g = idx & 31;
                const float* src = xb + r * F_DIM + g * 8;
                int dl = (r & 15) | ((g & 3) << 4);
                int base = (((r >> 4) * 8 + (g >> 2)) << 10) + dl * 16;
                if (g < 31) {
                    float2 v0 = *(const float2*)(src);
                    float2 v1 = *(const float2*)(src + 2);
                    float2 v2 = *(const float2*)(src + 4);
                    float2 v3 = *(const float2*)(src + 6);
                    bf16x8 pk = { (bf16)v0.x, (bf16)v0.y, (bf16)v1.x, (bf16)v1.y,
                                  (bf16)v2.x, (bf16)v2.y, (bf16)v3.x, (bf16)v3.y };
                    *(bf16x8*)(smem + base) = pk;
                } else {
                    // tail group: only c=248,249 valid (j=0,1); j>=2 zeroed above
                    float2 v0 = *(const float2*)(src);
                    bf16x2 pk = { (bf16)v0.x, (bf16)v0.y };
                    *(bf16x2*)(smem + base) = pk;
                }
            }
        }
    }
    __syncthreads();   // bar0: A-frags ready for all waves

    // ---- GEMM1: H'[64][256] = X @ Wp ; cols 250/251 are a_s/a_d ----
    f32x4 acc[4][4];
#pragma unroll
    for (int mt = 0; mt < 4; ++mt)
#pragma unroll
        for (int nti = 0; nti < 4; ++nti)
            acc[mt][nti] = (f32x4){0.f, 0.f, 0.f, 0.f};
    {
        const bf16x8* afrv = (const bf16x8*)(smem);
        const bf16x8* wpv  = (const bf16x8*)Wp;
#pragma unroll 2
        for (int kt = 0; kt < 8; ++kt) {
            bf16x8 af[4], bw[4];
#pragma unroll
            for (int mt = 0; mt < 4; ++mt)
                af[mt] = afrv[(mt * 8 + kt) * 64 + lane];
#pragma unroll
            for (int nti = 0; nti < 4; ++nti)
                bw[nti] = wpv[(kt * 16 + (w * 4 + nti)) * 64 + lane];
#pragma unroll
            for (int mt = 0; mt < 4; ++mt)
#pragma unroll
                for (int nti = 0; nti < 4; ++nti)
                    acc[mt][nti] = __builtin_amdgcn_mfma_f32_16x16x32_bf16(
                        af[mt], bw[nti], acc[mt][nti], 0, 0, 0);
        }
    }
    __syncthreads();   // bar1: all waves done reading A-frags before overwrite

    // write H -> LDS Hs[f][s] bf16 (swizzled), mask f<250 so rows 250-255
    // stay free for the AS/AD scratch; wave 3 extracts a_s/a_d from acc.
    {
#pragma unroll
        for (int mt = 0; mt < 4; ++mt) {
            int s0 = mt * 16 + fh * 4;
#pragma unroll
            for (int nti = 0; nti < 4; ++nti) {
                int f = w * 64 + nti * 16 + fl;
                if (f < F_DIM) {
                    f32x4 v = acc[mt][nti];
                    bf16x4 hv = { (bf16)v.x, (bf16)v.y, (bf16)v.z, (bf16)v.w };
                    *(bf16x4*)(smem + swz(f * 128 + s0 * 2)) = hv;
                }
            }
        }
        if (w == 3 && (fl == 10 || fl == 11)) {
            float* dst = (float*)(smem + (fl == 10 ? OFF_AS : OFF_AD));
#pragma unroll
            for (int mt = 0; mt < 4; ++mt) {
                f32x4 v = acc[mt][3];
#pragma unroll
                for (int i = 0; i < 4; ++i) dst[mt * 16 + fh * 4 + i] = v[i];
            }
        }
    }
    __syncthreads();   // bar2: Hs + AS/AD visible

    // softmax: thread -> (row d = tid>>2, 16-source chunk sq = tid&3);
    // row max + sum via 2 shuffles across the 4 sq-threads.
    {
        const float* AS  = (const float*)(smem + OFF_AS);
        const float* ADp = (const float*)(smem + OFF_AD);
        int d  = tid >> 2;
        int sq = tid & 3;
        float ad_v = ADp[d];
        f32x4 a0 = *(const f32x4*)(AS + sq * 16);
        f32x4 a1 = *(const f32x4*)(AS + sq * 16 + 4);
        f32x4 a2 = *(const f32x4*)(AS + sq * 16 + 8);
        f32x4 a3 = *(const f32x4*)(AS + sq * 16 + 12);
        float le[16];
#pragma unroll
        for (int k = 0; k < 4; ++k) {
            float e;
            e = a0[k] + ad_v; le[k]      = (e > 0.f) ? e : NEG_SLOPE * e;
            e = a1[k] + ad_v; le[4 + k]  = (e > 0.f) ? e : NEG_SLOPE * e;
            e = a2[k] + ad_v; le[8 + k]  = (e > 0.f) ? e : NEG_SLOPE * e;
            e = a3[k] + ad_v; le[12 + k] = (e > 0.f) ? e : NEG_SLOPE * e;
        }
        if (sq == 3) le[15] = -3.0e38f;   // exclude s=63 (only 63 sources)
        float md = le[0];
#pragma unroll
        for (int k = 1; k < 16; ++k) md = fmaxf(md, le[k]);
        md = fmaxf(md, __shfl_xor(md, 1));
        md = fmaxf(md, __shfl_xor(md, 2));
        float p[16], sum = 0.f;
#pragma unroll
        for (int k = 0; k < 16; ++k) { p[k] = __expf(le[k] - md); sum += p[k]; }
        sum += __shfl_xor(sum, 1);
        sum += __shfl_xor(sum, 2);
        float rz = 1.f / sum;
        bf16x8 pk0, pk1;
#pragma unroll
        for (int k = 0; k < 8; ++k) {
            pk0[k] = (bf16)(p[k] * rz);
            pk1[k] = (bf16)(p[8 + k] * rz);
        }
        int base = OFF_ALPHA + d * 128 + sq * 32;
        *(bf16x8*)(smem + swz(base))      = pk0;
        *(bf16x8*)(smem + swz(base + 16)) = pk1;
    }
    __syncthreads();   // bar3: alpha ready

    // ---- GEMM2: out[64][256] = alpha[64][64] @ Hs[64][256] ----
    f32x4 acc2[4][4];
#pragma unroll
    for (int mt = 0; mt < 4; ++mt)
#pragma unroll
        for (int nti = 0; nti < 4; ++nti)
            acc2[mt][nti] = (f32x4){0.f, 0.f, 0.f, 0.f};
    {
#pragma unroll
        for (int ks = 0; ks < 2; ++ks) {
            int kk = ks * 32 + fh * 8;
            bf16x8 aal[4], hbf[4];
#pragma unroll
            for (int mt = 0; mt < 4; ++mt) {
                int dd = mt * 16 + fl;
                aal[mt] = *(const bf16x8*)(smem + swz(OFF_ALPHA + dd * 128 + kk * 2));
            }
#pragma unroll
            for (int nti = 0; nti < 4; ++nti) {
                int f = w * 64 + nti * 16 + fl;
                hbf[nti] = *(const bf16x8*)(smem + swz(f * 128 + kk * 2));
            }
#pragma unroll
            for (int mt = 0; mt < 4; ++mt)
#pragma unroll
                for (int nti = 0; nti < 4; ++nti)
                    acc2[mt][nti] = __builtin_amdgcn_mfma_f32_16x16x32_bf16(
                        aal[mt], hbf[nti], acc2[mt][nti], 0, 0, 0);
        }
    }

    // epilogue: + bias, store fp32, mask r<63 / f<250
    float* ob = out + (size_t)b * (C_NODES * F_DIM);
#pragma unroll
    for (int mt = 0; mt < 4; ++mt) {
#pragma unroll
        for (int i = 0; i < 4; ++i) {
            int r = mt * 16 + fh * 4 + i;
            if (r < C_NODES) {
#pragma unroll
                for (int nti = 0; nti < 4; ++nti) {
                    int f = w * 64 + nti * 16 + fl;
                    if (f < F_DIM) ob[r * F_DIM + f] = acc2[mt][nti][i] + bv[nti];
                }
            }
        }
    }
}

extern "C" void kernel_launch(void* const* d_in, const int* in_sizes, int n_in,
                              void* d_out, int out_size, void* d_ws, size_t ws_size,
                              hipStream_t stream) {
    const float* x       = (const float*)d_in[0];
    const float* W       = (const float*)d_in[1];
    const float* att_src = (const float*)d_in[2];
    const float* att_dst = (const float*)d_in[3];
    const float* bias    = (const float*)d_in[4];
    float* out = (float*)d_out;
    bf16* Wp = (bf16*)d_ws;   // 65536 bf16 = 128 KB packed W (+score cols)

    gat_prep<<<256, 256, 0, stream>>>(W, att_src, att_dst, Wp);
    gat_main<<<4096, 256, 0, stream>>>(x, Wp, bias, out);
}